// Round 1
// baseline (1184.352 us; speedup 1.0000x reference)
//
#include <hip/hip_runtime.h>

#define NB 2
#define NC 256
#define NHH 40
#define NSP 64000      // 40*40*40
#define PL 1600        // 40*40
#define SCALE 0.17677669529663687f  // 1/sqrt(32)

typedef unsigned short u16;
typedef unsigned int   u32;

__device__ __forceinline__ float bf2f(u16 u) {
    union { u32 i; float f; } c; c.i = ((u32)u) << 16; return c.f;
}
__device__ __forceinline__ u16 f2bf(float f) {
    union { u32 i; float f; } c; c.f = f; u32 x = c.i;
    return (u16)((x + 0x7fffu + ((x >> 16) & 1u)) >> 16);
}

// ---------------------------------------------------------------------------
// QKV: q/k/v[b][o][n] = sum_c W[o][c] * x[b][c][n] + bias[o], stored bf16
// Tile: 64 o x 64 n per block, 256 threads, 4x4 per thread, K-chunk 16.
// ---------------------------------------------------------------------------
__global__ __launch_bounds__(256) void qkv_kernel(
    const float* __restrict__ x,
    const float* __restrict__ wq, const float* __restrict__ bq,
    const float* __restrict__ wk, const float* __restrict__ bk,
    const float* __restrict__ wv, const float* __restrict__ bv,
    u16* __restrict__ q, u16* __restrict__ k, u16* __restrict__ v)
{
    const int b  = blockIdx.z;
    const int o0 = blockIdx.y << 6;
    const int n0 = blockIdx.x << 6;
    const int t  = threadIdx.x;
    const int tx = t & 15, ty = t >> 4;

    __shared__ float xs[16][64];       // [cc][n]
    __shared__ float ws[3][16][68];    // [mat][cc][o], pad 68 keeps f4 align + 2-way banks

    float acc[3][4][4];
#pragma unroll
    for (int m = 0; m < 3; m++)
#pragma unroll
        for (int i = 0; i < 4; i++)
#pragma unroll
            for (int j = 0; j < 4; j++) acc[m][i][j] = 0.f;

    const float* xb = x + (size_t)b * NC * NSP;
    const float* wmat[3] = { wq, wk, wv };

    const int lo = t >> 2;            // 0..63  (o index for W staging)
    const int lc = (t & 3) << 2;      // 0,4,8,12

    for (int c0 = 0; c0 < NC; c0 += 16) {
        // stage x tile: each thread one float4 (row cc = t>>4, cols (t&15)*4)
        {
            const int cc = t >> 4;
            const int nn = (t & 15) << 2;
            const float4 xv = *(const float4*)(xb + (size_t)(c0 + cc) * NSP + n0 + nn);
            *(float4*)&xs[cc][nn] = xv;
        }
        // stage W tiles transposed to [cc][o]
#pragma unroll
        for (int m = 0; m < 3; m++) {
            const float4 w4 = *(const float4*)(wmat[m] + (size_t)(o0 + lo) * NC + c0 + lc);
            ws[m][lc + 0][lo] = w4.x;
            ws[m][lc + 1][lo] = w4.y;
            ws[m][lc + 2][lo] = w4.z;
            ws[m][lc + 3][lo] = w4.w;
        }
        __syncthreads();

#pragma unroll
        for (int cc = 0; cc < 16; cc++) {
            const float4 xvf = *(const float4*)&xs[cc][tx << 2];
            const float xv[4] = { xvf.x, xvf.y, xvf.z, xvf.w };
#pragma unroll
            for (int m = 0; m < 3; m++) {
                const float4 wvf = *(const float4*)&ws[m][cc][ty << 2];
                const float wv4[4] = { wvf.x, wvf.y, wvf.z, wvf.w };
#pragma unroll
                for (int i = 0; i < 4; i++)
#pragma unroll
                    for (int j = 0; j < 4; j++)
                        acc[m][i][j] += wv4[i] * xv[j];
            }
        }
        __syncthreads();
    }

    u16* outp[3] = { q, k, v };
    const float* bias[3] = { bq, bk, bv };
#pragma unroll
    for (int m = 0; m < 3; m++) {
#pragma unroll
        for (int i = 0; i < 4; i++) {
            const int o = o0 + (ty << 2) + i;
            const float bb = bias[m][o];
            ushort4 pk;
            pk.x = f2bf(acc[m][i][0] + bb);
            pk.y = f2bf(acc[m][i][1] + bb);
            pk.z = f2bf(acc[m][i][2] + bb);
            pk.w = f2bf(acc[m][i][3] + bb);
            *(ushort4*)(outp[m] + (size_t)b * NC * NSP + (size_t)o * NSP + n0 + (tx << 2)) = pk;
        }
    }
}

// ---------------------------------------------------------------------------
// Attention: one block per slice (b,ch,h) = contiguous 1600 elems.
// S = scale * Q K^T (40x40, padded 48), softmax rows (x3 folded into 1/sum),
// O = P V, write bf16. 256 threads, 3x3 per-thread register tiles on 48x48.
// ---------------------------------------------------------------------------
__global__ __launch_bounds__(256) void attn_kernel(
    const u16* __restrict__ q, const u16* __restrict__ k,
    const u16* __restrict__ v, u16* __restrict__ a)
{
    const int s = blockIdx.x;                  // 0 .. NB*NC*NHH-1
    const size_t base = (size_t)s * PL;
    const int t = threadIdx.x;
    const int tx = t & 15, ty = t >> 4;

    __shared__ float qs[48][40];
    __shared__ float ks[48][40];
    __shared__ float vs[48][40];
    __shared__ float ps[48][48];

    // load q,k,v slices (400 ushort4 each), convert to fp32
    for (int i4 = t; i4 < 400; i4 += 256) {
        const int w = i4 / 10;
        const int d = (i4 % 10) << 2;
        const ushort4 qv = *(const ushort4*)(q + base + (i4 << 2));
        const ushort4 kv = *(const ushort4*)(k + base + (i4 << 2));
        const ushort4 vv = *(const ushort4*)(v + base + (i4 << 2));
        float4 f;
        f.x = bf2f(qv.x); f.y = bf2f(qv.y); f.z = bf2f(qv.z); f.w = bf2f(qv.w);
        *(float4*)&qs[w][d] = f;
        f.x = bf2f(kv.x); f.y = bf2f(kv.y); f.z = bf2f(kv.z); f.w = bf2f(kv.w);
        *(float4*)&ks[w][d] = f;
        f.x = bf2f(vv.x); f.y = bf2f(vv.y); f.z = bf2f(vv.z); f.w = bf2f(vv.w);
        *(float4*)&vs[w][d] = f;
    }
    // zero the pad rows 40..47
    for (int idx = 1600 + t; idx < 1920; idx += 256) {
        const int w = idx / 40, d = idx % 40;
        qs[w][d] = 0.f; ks[w][d] = 0.f; vs[w][d] = 0.f;
    }
    __syncthreads();

    const int r0 = ty * 3;   // 3 rows per thread, covers 48
    const int c0 = tx * 3;   // 3 cols per thread, covers 48

    // S phase
    float sa[3][3];
#pragma unroll
    for (int i = 0; i < 3; i++)
#pragma unroll
        for (int j = 0; j < 3; j++) sa[i][j] = 0.f;

    for (int d4 = 0; d4 < 40; d4 += 4) {
        float4 qv[3], kv[3];
#pragma unroll
        for (int i = 0; i < 3; i++) qv[i] = *(const float4*)&qs[r0 + i][d4];
#pragma unroll
        for (int j = 0; j < 3; j++) kv[j] = *(const float4*)&ks[c0 + j][d4];
#pragma unroll
        for (int i = 0; i < 3; i++)
#pragma unroll
            for (int j = 0; j < 3; j++)
                sa[i][j] += qv[i].x * kv[j].x + qv[i].y * kv[j].y
                          + qv[i].z * kv[j].z + qv[i].w * kv[j].w;
    }
#pragma unroll
    for (int i = 0; i < 3; i++)
#pragma unroll
        for (int j = 0; j < 3; j++)
            ps[r0 + i][c0 + j] = sa[i][j] * SCALE;
    __syncthreads();

    // softmax per row; fold the x3 (three identical branches) into the norm
    if (t < 40) {
        float mx = -1e30f;
#pragma unroll 8
        for (int j = 0; j < 40; j++) mx = fmaxf(mx, ps[t][j]);
        float sum = 0.f;
#pragma unroll 8
        for (int j = 0; j < 40; j++) {
            const float e = __expf(ps[t][j] - mx);
            ps[t][j] = e; sum += e;
        }
        const float inv = 3.0f / sum;
#pragma unroll 8
        for (int j = 0; j < 40; j++) ps[t][j] *= inv;
    }
    __syncthreads();

    // O = P @ V   (rows w = r0.., cols d = c0..)
    float oa[3][3];
#pragma unroll
    for (int i = 0; i < 3; i++)
#pragma unroll
        for (int j = 0; j < 3; j++) oa[i][j] = 0.f;

    for (int wp_ = 0; wp_ < 40; wp_++) {
        float pv[3], vv[3];
#pragma unroll
        for (int i = 0; i < 3; i++) pv[i] = ps[r0 + i][wp_];
#pragma unroll
        for (int j = 0; j < 3; j++) vv[j] = vs[wp_][c0 + j];
#pragma unroll
        for (int i = 0; i < 3; i++)
#pragma unroll
            for (int j = 0; j < 3; j++) oa[i][j] += pv[i] * vv[j];
    }
#pragma unroll
    for (int i = 0; i < 3; i++)
#pragma unroll
        for (int j = 0; j < 3; j++) {
            const int w = r0 + i, d = c0 + j;
            if (w < 40 && d < 40) a[base + w * 40 + d] = f2bf(oa[i][j]);
        }
}

// ---------------------------------------------------------------------------
// Proj: out[b][o][n] = sum_c wp[o][c] * a[b][c][n] + bp[o], fp32 out
// ---------------------------------------------------------------------------
__global__ __launch_bounds__(256) void proj_kernel(
    const u16* __restrict__ a, const float* __restrict__ wp,
    const float* __restrict__ bp, float* __restrict__ out)
{
    const int b  = blockIdx.z;
    const int o0 = blockIdx.y << 6;
    const int n0 = blockIdx.x << 6;
    const int t  = threadIdx.x;
    const int tx = t & 15, ty = t >> 4;

    __shared__ float xs[16][64];
    __shared__ float ws[16][68];

    float acc[4][4];
#pragma unroll
    for (int i = 0; i < 4; i++)
#pragma unroll
        for (int j = 0; j < 4; j++) acc[i][j] = 0.f;

    const u16* ab = a + (size_t)b * NC * NSP;
    const int lo = t >> 2;
    const int lc = (t & 3) << 2;

    for (int c0 = 0; c0 < NC; c0 += 16) {
        {
            const int cc = t >> 4;
            const int nn = (t & 15) << 2;
            const ushort4 av = *(const ushort4*)(ab + (size_t)(c0 + cc) * NSP + n0 + nn);
            float4 f;
            f.x = bf2f(av.x); f.y = bf2f(av.y); f.z = bf2f(av.z); f.w = bf2f(av.w);
            *(float4*)&xs[cc][nn] = f;
        }
        {
            const float4 w4 = *(const float4*)(wp + (size_t)(o0 + lo) * NC + c0 + lc);
            ws[lc + 0][lo] = w4.x;
            ws[lc + 1][lo] = w4.y;
            ws[lc + 2][lo] = w4.z;
            ws[lc + 3][lo] = w4.w;
        }
        __syncthreads();

#pragma unroll
        for (int cc = 0; cc < 16; cc++) {
            const float4 xvf = *(const float4*)&xs[cc][tx << 2];
            const float xv[4] = { xvf.x, xvf.y, xvf.z, xvf.w };
            const float4 wvf = *(const float4*)&ws[cc][ty << 2];
            const float wv4[4] = { wvf.x, wvf.y, wvf.z, wvf.w };
#pragma unroll
            for (int i = 0; i < 4; i++)
#pragma unroll
                for (int j = 0; j < 4; j++)
                    acc[i][j] += wv4[i] * xv[j];
        }
        __syncthreads();
    }

#pragma unroll
    for (int i = 0; i < 4; i++) {
        const int o = o0 + (ty << 2) + i;
        const float bb = bp[o];
        float4 o4;
        o4.x = acc[i][0] + bb;
        o4.y = acc[i][1] + bb;
        o4.z = acc[i][2] + bb;
        o4.w = acc[i][3] + bb;
        *(float4*)(out + (size_t)b * NC * NSP + (size_t)o * NSP + n0 + (tx << 2)) = o4;
    }
}

extern "C" void kernel_launch(void* const* d_in, const int* in_sizes, int n_in,
                              void* d_out, int out_size, void* d_ws, size_t ws_size,
                              hipStream_t stream)
{
    const float* x  = (const float*)d_in[0];
    const float* wq = (const float*)d_in[1];
    const float* bq = (const float*)d_in[2];
    const float* wk = (const float*)d_in[3];
    const float* bk = (const float*)d_in[4];
    const float* wv = (const float*)d_in[5];
    const float* bv = (const float*)d_in[6];
    const float* wp = (const float*)d_in[7];
    const float* bp = (const float*)d_in[8];
    float* out = (float*)d_out;

    const size_t QE = (size_t)NB * NC * NSP;   // 32,768,000 elems
    u16* qb = (u16*)d_ws;
    u16* kb = qb + QE;
    u16* vb = kb + QE;
    u16* ab = vb + QE;                         // total 262.1 MB bf16

    qkv_kernel<<<dim3(NSP / 64, NC / 64, NB), 256, 0, stream>>>(
        x, wq, bq, wk, bk, wv, bv, qb, kb, vb);
    attn_kernel<<<dim3(NB * NC * NHH), 256, 0, stream>>>(qb, kb, vb, ab);
    proj_kernel<<<dim3(NSP / 64, NC / 64, NB), 256, 0, stream>>>(ab, wp, bp, out);
}

// Round 2
// 540.420 us; speedup vs baseline: 2.1915x; 2.1915x over previous
//
#include <hip/hip_runtime.h>

#define NB 2
#define NC 256
#define NHH 40
#define NSP 64000      // 40*40*40
#define PL 1600        // 40*40
#define SCALE 0.17677669529663687f  // 1/sqrt(32)

typedef unsigned short u16;
typedef unsigned int   u32;

typedef __attribute__((ext_vector_type(8))) short bf16x8;  // 8 bf16 = 4 VGPRs
typedef __attribute__((ext_vector_type(4))) float f32x4;

__device__ __forceinline__ float bf2f(u16 u) {
    union { u32 i; float f; } c; c.i = ((u32)u) << 16; return c.f;
}
__device__ __forceinline__ u16 f2bf(float f) {
    union { u32 i; float f; } c; c.f = f; u32 x = c.i;
    return (u16)((x + 0x7fffu + ((x >> 16) & 1u)) >> 16);
}
__device__ __forceinline__ u32 pack2(float a, float b) {
    return (u32)f2bf(a) | ((u32)f2bf(b) << 16);
}
__device__ __forceinline__ f32x4 zero4() {
    f32x4 z; z[0] = 0.f; z[1] = 0.f; z[2] = 0.f; z[3] = 0.f; return z;
}

// ---------------------------------------------------------------------------
// QKV via MFMA: q/k/v[b][o][n] = sum_c W[o][c] * x[b][c][n] + bias, bf16 out.
// Block: 256 thr (4 waves), tile M=256 (o, 64/wave) x N=64 (n), K=256.
// X staged once to LDS transposed [n][c] (pad 264); W double-buffered K=32.
// ---------------------------------------------------------------------------
__global__ __launch_bounds__(256, 2) void qkv_mfma(
    const float* __restrict__ x,
    const float* __restrict__ wq, const float* __restrict__ bq,
    const float* __restrict__ wk, const float* __restrict__ bk,
    const float* __restrict__ wv, const float* __restrict__ bv,
    u16* __restrict__ q, u16* __restrict__ k, u16* __restrict__ v)
{
    const int b    = blockIdx.z;
    const int n0   = blockIdx.x * 64;
    const int t    = threadIdx.x;
    const int lane = t & 63;
    const int wid  = t >> 6;
    const int o0w  = wid * 64;

    __shared__ u16 xs[64][264];        // [n][c], pad 264 (stride 528B -> 2-way only)
    __shared__ u16 wsm[2][256][40];    // [buf][o][c(32, pad 40)]

    const float* xb = x + (size_t)b * NC * NSP;

    // ---- stage X (entire K) : transpose to [n][c], fp32 -> bf16 pairs ----
    {
        const int p  = t >> 4;          // 0..15 (c-pair)
        const int nn = (t & 15) << 2;   // 0..60
#pragma unroll
        for (int it = 0; it < 8; ++it) {
            const int c = (it * 16 + p) * 2;
            const float4 fa = *(const float4*)(xb + (size_t)c * NSP + n0 + nn);
            const float4 fb = *(const float4*)(xb + (size_t)(c + 1) * NSP + n0 + nn);
            *(u32*)&xs[nn + 0][c] = pack2(fa.x, fb.x);
            *(u32*)&xs[nn + 1][c] = pack2(fa.y, fb.y);
            *(u32*)&xs[nn + 2][c] = pack2(fa.z, fb.z);
            *(u32*)&xs[nn + 3][c] = pack2(fa.w, fb.w);
        }
    }

    // ---- stage W chunk for step 0 (wq, kc=0) ----
    const int wo = t >> 3;          // 0..31
    const int wc = (t & 7) << 2;    // 0,4,..,28
    {
#pragma unroll
        for (int r = 0; r < 8; ++r) {
            const int o = r * 32 + wo;
            const float4 w4 = *(const float4*)(wq + (size_t)o * NC + wc);
            ushort4 pk;
            pk.x = f2bf(w4.x); pk.y = f2bf(w4.y); pk.z = f2bf(w4.z); pk.w = f2bf(w4.w);
            *(ushort4*)&wsm[0][o][wc] = pk;
        }
    }
    __syncthreads();

    f32x4 acc[4][4];
#pragma unroll
    for (int i = 0; i < 4; ++i)
#pragma unroll
        for (int j = 0; j < 4; ++j) acc[i][j] = zero4();

    const int row = lane & 15;
    const int kg  = (lane >> 4) << 3;   // 0,8,16,24

    int cur = 0;
    for (int step = 0; step < 24; ++step) {
        const int m  = step >> 3;
        const int kc = step & 7;
        const bool pf = (step + 1 < 24);

        // phase 1: issue global prefetch of next W chunk into regs
        float4 wreg[8];
        if (pf) {
            const int m2  = (step + 1) >> 3;
            const int kc2 = (step + 1) & 7;
            const float* wm = (m2 == 0) ? wq : ((m2 == 1) ? wk : wv);
#pragma unroll
            for (int r = 0; r < 8; ++r) {
                const int o = r * 32 + wo;
                wreg[r] = *(const float4*)(wm + (size_t)o * NC + kc2 * 32 + wc);
            }
        }

        // phase 2: compute current chunk
        bf16x8 af[4], bfr[4];
#pragma unroll
        for (int i = 0; i < 4; ++i)
            af[i] = *(const bf16x8*)&wsm[cur][o0w + 16 * i + row][kg];
#pragma unroll
        for (int j = 0; j < 4; ++j)
            bfr[j] = *(const bf16x8*)&xs[16 * j + row][kc * 32 + kg];
#pragma unroll
        for (int i = 0; i < 4; ++i)
#pragma unroll
            for (int j = 0; j < 4; ++j)
                acc[i][j] = __builtin_amdgcn_mfma_f32_16x16x32_bf16(
                    af[i], bfr[j], acc[i][j], 0, 0, 0);

        __syncthreads();   // all reads of wsm[cur^1] (prev step) + this step done

        // phase 4: write prefetched W into the other buffer
        if (pf) {
#pragma unroll
            for (int r = 0; r < 8; ++r) {
                const int o = r * 32 + wo;
                ushort4 pk;
                pk.x = f2bf(wreg[r].x); pk.y = f2bf(wreg[r].y);
                pk.z = f2bf(wreg[r].z); pk.w = f2bf(wreg[r].w);
                *(ushort4*)&wsm[cur ^ 1][o][wc] = pk;
            }
        }

        // epilogue per mat
        if (kc == 7) {
            u16* op = ((m == 0) ? q : ((m == 1) ? k : v)) + (size_t)b * NC * NSP;
            const float* bm = (m == 0) ? bq : ((m == 1) ? bk : bv);
#pragma unroll
            for (int i = 0; i < 4; ++i) {
#pragma unroll
                for (int r = 0; r < 4; ++r) {
                    const int o = o0w + 16 * i + ((lane >> 4) << 2) + r;
                    const float bb = bm[o];
#pragma unroll
                    for (int j = 0; j < 4; ++j) {
                        const int n = n0 + 16 * j + row;
                        op[(size_t)o * NSP + n] = f2bf(acc[i][j][r] + bb);
                    }
                }
            }
#pragma unroll
            for (int i = 0; i < 4; ++i)
#pragma unroll
                for (int j = 0; j < 4; ++j) acc[i][j] = zero4();
        }

        __syncthreads();
        cur ^= 1;
    }
}

// ---------------------------------------------------------------------------
// Attention (unchanged this round): one block per slice (b,ch,h).
// ---------------------------------------------------------------------------
__global__ __launch_bounds__(256) void attn_kernel(
    const u16* __restrict__ q, const u16* __restrict__ k,
    const u16* __restrict__ v, u16* __restrict__ a)
{
    const int s = blockIdx.x;
    const size_t base = (size_t)s * PL;
    const int t = threadIdx.x;
    const int tx = t & 15, ty = t >> 4;

    __shared__ float qs[48][40];
    __shared__ float ks[48][40];
    __shared__ float vs[48][40];
    __shared__ float ps[48][48];

    for (int i4 = t; i4 < 400; i4 += 256) {
        const int w = i4 / 10;
        const int d = (i4 % 10) << 2;
        const ushort4 qv = *(const ushort4*)(q + base + (i4 << 2));
        const ushort4 kv = *(const ushort4*)(k + base + (i4 << 2));
        const ushort4 vv = *(const ushort4*)(v + base + (i4 << 2));
        float4 f;
        f.x = bf2f(qv.x); f.y = bf2f(qv.y); f.z = bf2f(qv.z); f.w = bf2f(qv.w);
        *(float4*)&qs[w][d] = f;
        f.x = bf2f(kv.x); f.y = bf2f(kv.y); f.z = bf2f(kv.z); f.w = bf2f(kv.w);
        *(float4*)&ks[w][d] = f;
        f.x = bf2f(vv.x); f.y = bf2f(vv.y); f.z = bf2f(vv.z); f.w = bf2f(vv.w);
        *(float4*)&vs[w][d] = f;
    }
    for (int idx = 1600 + t; idx < 1920; idx += 256) {
        const int w = idx / 40, d = idx % 40;
        qs[w][d] = 0.f; ks[w][d] = 0.f; vs[w][d] = 0.f;
    }
    __syncthreads();

    const int r0 = ty * 3;
    const int c0 = tx * 3;

    float sa[3][3];
#pragma unroll
    for (int i = 0; i < 3; i++)
#pragma unroll
        for (int j = 0; j < 3; j++) sa[i][j] = 0.f;

    for (int d4 = 0; d4 < 40; d4 += 4) {
        float4 qv[3], kv[3];
#pragma unroll
        for (int i = 0; i < 3; i++) qv[i] = *(const float4*)&qs[r0 + i][d4];
#pragma unroll
        for (int j = 0; j < 3; j++) kv[j] = *(const float4*)&ks[c0 + j][d4];
#pragma unroll
        for (int i = 0; i < 3; i++)
#pragma unroll
            for (int j = 0; j < 3; j++)
                sa[i][j] += qv[i].x * kv[j].x + qv[i].y * kv[j].y
                          + qv[i].z * kv[j].z + qv[i].w * kv[j].w;
    }
#pragma unroll
    for (int i = 0; i < 3; i++)
#pragma unroll
        for (int j = 0; j < 3; j++)
            ps[r0 + i][c0 + j] = sa[i][j] * SCALE;
    __syncthreads();

    if (t < 40) {
        float mx = -1e30f;
#pragma unroll 8
        for (int j = 0; j < 40; j++) mx = fmaxf(mx, ps[t][j]);
        float sum = 0.f;
#pragma unroll 8
        for (int j = 0; j < 40; j++) {
            const float e = __expf(ps[t][j] - mx);
            ps[t][j] = e; sum += e;
        }
        const float inv = 3.0f / sum;
#pragma unroll 8
        for (int j = 0; j < 40; j++) ps[t][j] *= inv;
    }
    __syncthreads();

    float oa[3][3];
#pragma unroll
    for (int i = 0; i < 3; i++)
#pragma unroll
        for (int j = 0; j < 3; j++) oa[i][j] = 0.f;

    for (int wp_ = 0; wp_ < 40; wp_++) {
        float pv[3], vv[3];
#pragma unroll
        for (int i = 0; i < 3; i++) pv[i] = ps[r0 + i][wp_];
#pragma unroll
        for (int j = 0; j < 3; j++) vv[j] = vs[wp_][c0 + j];
#pragma unroll
        for (int i = 0; i < 3; i++)
#pragma unroll
            for (int j = 0; j < 3; j++) oa[i][j] += pv[i] * vv[j];
    }
#pragma unroll
    for (int i = 0; i < 3; i++)
#pragma unroll
        for (int j = 0; j < 3; j++) {
            const int w = r0 + i, d = c0 + j;
            if (w < 40 && d < 40) a[base + w * 40 + d] = f2bf(oa[i][j]);
        }
}

// ---------------------------------------------------------------------------
// Proj via MFMA: out[b][o][n] = sum_c wp[o][c] * a[b][c][n] + bp[o], fp32 out.
// Same structure as qkv_mfma, single mat (8 steps), bf16 input (no cvt on X).
// ---------------------------------------------------------------------------
__global__ __launch_bounds__(256, 2) void proj_mfma(
    const u16* __restrict__ a, const float* __restrict__ wp,
    const float* __restrict__ bp, float* __restrict__ out)
{
    const int b    = blockIdx.z;
    const int n0   = blockIdx.x * 64;
    const int t    = threadIdx.x;
    const int lane = t & 63;
    const int wid  = t >> 6;
    const int o0w  = wid * 64;

    __shared__ u16 xs[64][264];
    __shared__ u16 wsm[2][256][40];

    const u16* ab = a + (size_t)b * NC * NSP;

    // stage A (entire K), transpose [n][c]
    {
        const int p  = t >> 4;
        const int nn = (t & 15) << 2;
#pragma unroll
        for (int it = 0; it < 8; ++it) {
            const int c = (it * 16 + p) * 2;
            const ushort4 ua = *(const ushort4*)(ab + (size_t)c * NSP + n0 + nn);
            const ushort4 ub = *(const ushort4*)(ab + (size_t)(c + 1) * NSP + n0 + nn);
            *(u32*)&xs[nn + 0][c] = (u32)ua.x | ((u32)ub.x << 16);
            *(u32*)&xs[nn + 1][c] = (u32)ua.y | ((u32)ub.y << 16);
            *(u32*)&xs[nn + 2][c] = (u32)ua.z | ((u32)ub.z << 16);
            *(u32*)&xs[nn + 3][c] = (u32)ua.w | ((u32)ub.w << 16);
        }
    }

    const int wo = t >> 3;
    const int wc = (t & 7) << 2;
    {
#pragma unroll
        for (int r = 0; r < 8; ++r) {
            const int o = r * 32 + wo;
            const float4 w4 = *(const float4*)(wp + (size_t)o * NC + wc);
            ushort4 pk;
            pk.x = f2bf(w4.x); pk.y = f2bf(w4.y); pk.z = f2bf(w4.z); pk.w = f2bf(w4.w);
            *(ushort4*)&wsm[0][o][wc] = pk;
        }
    }
    __syncthreads();

    f32x4 acc[4][4];
#pragma unroll
    for (int i = 0; i < 4; ++i)
#pragma unroll
        for (int j = 0; j < 4; ++j) acc[i][j] = zero4();

    const int row = lane & 15;
    const int kg  = (lane >> 4) << 3;

    int cur = 0;
    for (int step = 0; step < 8; ++step) {
        const bool pf = (step + 1 < 8);
        float4 wreg[8];
        if (pf) {
            const int kc2 = step + 1;
#pragma unroll
            for (int r = 0; r < 8; ++r) {
                const int o = r * 32 + wo;
                wreg[r] = *(const float4*)(wp + (size_t)o * NC + kc2 * 32 + wc);
            }
        }

        bf16x8 af[4], bfr[4];
#pragma unroll
        for (int i = 0; i < 4; ++i)
            af[i] = *(const bf16x8*)&wsm[cur][o0w + 16 * i + row][kg];
#pragma unroll
        for (int j = 0; j < 4; ++j)
            bfr[j] = *(const bf16x8*)&xs[16 * j + row][step * 32 + kg];
#pragma unroll
        for (int i = 0; i < 4; ++i)
#pragma unroll
            for (int j = 0; j < 4; ++j)
                acc[i][j] = __builtin_amdgcn_mfma_f32_16x16x32_bf16(
                    af[i], bfr[j], acc[i][j], 0, 0, 0);

        __syncthreads();

        if (pf) {
#pragma unroll
            for (int r = 0; r < 8; ++r) {
                const int o = r * 32 + wo;
                ushort4 pk;
                pk.x = f2bf(wreg[r].x); pk.y = f2bf(wreg[r].y);
                pk.z = f2bf(wreg[r].z); pk.w = f2bf(wreg[r].w);
                *(ushort4*)&wsm[cur ^ 1][o][wc] = pk;
            }
        }
        __syncthreads();
        cur ^= 1;
    }

    float* ob = out + (size_t)b * NC * NSP;
#pragma unroll
    for (int i = 0; i < 4; ++i) {
#pragma unroll
        for (int r = 0; r < 4; ++r) {
            const int o = o0w + 16 * i + ((lane >> 4) << 2) + r;
            const float bb = bp[o];
#pragma unroll
            for (int j = 0; j < 4; ++j) {
                const int n = n0 + 16 * j + row;
                ob[(size_t)o * NSP + n] = acc[i][j][r] + bb;
            }
        }
    }
}

extern "C" void kernel_launch(void* const* d_in, const int* in_sizes, int n_in,
                              void* d_out, int out_size, void* d_ws, size_t ws_size,
                              hipStream_t stream)
{
    const float* x  = (const float*)d_in[0];
    const float* wq = (const float*)d_in[1];
    const float* bq = (const float*)d_in[2];
    const float* wk = (const float*)d_in[3];
    const float* bk = (const float*)d_in[4];
    const float* wv = (const float*)d_in[5];
    const float* bv = (const float*)d_in[6];
    const float* wp = (const float*)d_in[7];
    const float* bp = (const float*)d_in[8];
    float* out = (float*)d_out;

    const size_t QE = (size_t)NB * NC * NSP;
    u16* qb = (u16*)d_ws;
    u16* kb = qb + QE;
    u16* vb = kb + QE;
    u16* ab = vb + QE;

    qkv_mfma<<<dim3(NSP / 64, 1, NB), 256, 0, stream>>>(
        x, wq, bq, wk, bk, wv, bv, qb, kb, vb);
    attn_kernel<<<dim3(NB * NC * NHH), 256, 0, stream>>>(qb, kb, vb, ab);
    proj_mfma<<<dim3(NSP / 64, 1, NB), 256, 0, stream>>>(ab, wp, bp, out);
}

// Round 3
// 281.519 us; speedup vs baseline: 4.2070x; 1.9197x over previous
//
#include <hip/hip_runtime.h>

#define NB 2
#define NC 256
#define NHH 40
#define NSP 64000      // 40*40*40
#define PL 1600        // 40*40
#define SCALE 0.17677669529663687f  // 1/sqrt(32)

typedef unsigned short u16;
typedef unsigned int   u32;

typedef __attribute__((ext_vector_type(8))) short bf16x8;  // 8 bf16 = 4 VGPRs
typedef __attribute__((ext_vector_type(4))) float f32x4;

__device__ __forceinline__ float bf2f(u16 u) {
    union { u32 i; float f; } c; c.i = ((u32)u) << 16; return c.f;
}
__device__ __forceinline__ u16 f2bf(float f) {
    union { u32 i; float f; } c; c.f = f; u32 x = c.i;
    return (u16)((x + 0x7fffu + ((x >> 16) & 1u)) >> 16);
}
__device__ __forceinline__ u32 pack2(float a, float b) {
    return (u32)f2bf(a) | ((u32)f2bf(b) << 16);
}
__device__ __forceinline__ f32x4 zero4() {
    f32x4 z; z[0] = 0.f; z[1] = 0.f; z[2] = 0.f; z[3] = 0.f; return z;
}
__device__ __forceinline__ bf16x8 zero8() {
    bf16x8 z;
#pragma unroll
    for (int e = 0; e < 8; ++e) z[e] = 0;
    return z;
}

// ---------------------------------------------------------------------------
// QKV via MFMA (unchanged from round 2)
// ---------------------------------------------------------------------------
__global__ __launch_bounds__(256, 2) void qkv_mfma(
    const float* __restrict__ x,
    const float* __restrict__ wq, const float* __restrict__ bq,
    const float* __restrict__ wk, const float* __restrict__ bk,
    const float* __restrict__ wv, const float* __restrict__ bv,
    u16* __restrict__ q, u16* __restrict__ k, u16* __restrict__ v)
{
    const int b    = blockIdx.z;
    const int n0   = blockIdx.x * 64;
    const int t    = threadIdx.x;
    const int lane = t & 63;
    const int wid  = t >> 6;
    const int o0w  = wid * 64;

    __shared__ u16 xs[64][264];
    __shared__ u16 wsm[2][256][40];

    const float* xb = x + (size_t)b * NC * NSP;

    {
        const int p  = t >> 4;
        const int nn = (t & 15) << 2;
#pragma unroll
        for (int it = 0; it < 8; ++it) {
            const int c = (it * 16 + p) * 2;
            const float4 fa = *(const float4*)(xb + (size_t)c * NSP + n0 + nn);
            const float4 fb = *(const float4*)(xb + (size_t)(c + 1) * NSP + n0 + nn);
            *(u32*)&xs[nn + 0][c] = pack2(fa.x, fb.x);
            *(u32*)&xs[nn + 1][c] = pack2(fa.y, fb.y);
            *(u32*)&xs[nn + 2][c] = pack2(fa.z, fb.z);
            *(u32*)&xs[nn + 3][c] = pack2(fa.w, fb.w);
        }
    }

    const int wo = t >> 3;
    const int wc = (t & 7) << 2;
    {
#pragma unroll
        for (int r = 0; r < 8; ++r) {
            const int o = r * 32 + wo;
            const float4 w4 = *(const float4*)(wq + (size_t)o * NC + wc);
            ushort4 pk;
            pk.x = f2bf(w4.x); pk.y = f2bf(w4.y); pk.z = f2bf(w4.z); pk.w = f2bf(w4.w);
            *(ushort4*)&wsm[0][o][wc] = pk;
        }
    }
    __syncthreads();

    f32x4 acc[4][4];
#pragma unroll
    for (int i = 0; i < 4; ++i)
#pragma unroll
        for (int j = 0; j < 4; ++j) acc[i][j] = zero4();

    const int row = lane & 15;
    const int kg  = (lane >> 4) << 3;

    int cur = 0;
    for (int step = 0; step < 24; ++step) {
        const int m  = step >> 3;
        const int kc = step & 7;
        const bool pf = (step + 1 < 24);

        float4 wreg[8];
        if (pf) {
            const int m2  = (step + 1) >> 3;
            const int kc2 = (step + 1) & 7;
            const float* wm = (m2 == 0) ? wq : ((m2 == 1) ? wk : wv);
#pragma unroll
            for (int r = 0; r < 8; ++r) {
                const int o = r * 32 + wo;
                wreg[r] = *(const float4*)(wm + (size_t)o * NC + kc2 * 32 + wc);
            }
        }

        bf16x8 af[4], bfr[4];
#pragma unroll
        for (int i = 0; i < 4; ++i)
            af[i] = *(const bf16x8*)&wsm[cur][o0w + 16 * i + row][kg];
#pragma unroll
        for (int j = 0; j < 4; ++j)
            bfr[j] = *(const bf16x8*)&xs[16 * j + row][kc * 32 + kg];
#pragma unroll
        for (int i = 0; i < 4; ++i)
#pragma unroll
            for (int j = 0; j < 4; ++j)
                acc[i][j] = __builtin_amdgcn_mfma_f32_16x16x32_bf16(
                    af[i], bfr[j], acc[i][j], 0, 0, 0);

        __syncthreads();

        if (pf) {
#pragma unroll
            for (int r = 0; r < 8; ++r) {
                const int o = r * 32 + wo;
                ushort4 pk;
                pk.x = f2bf(wreg[r].x); pk.y = f2bf(wreg[r].y);
                pk.z = f2bf(wreg[r].z); pk.w = f2bf(wreg[r].w);
                *(ushort4*)&wsm[cur ^ 1][o][wc] = pk;
            }
        }

        if (kc == 7) {
            u16* op = ((m == 0) ? q : ((m == 1) ? k : v)) + (size_t)b * NC * NSP;
            const float* bm = (m == 0) ? bq : ((m == 1) ? bk : bv);
#pragma unroll
            for (int i = 0; i < 4; ++i) {
#pragma unroll
                for (int r = 0; r < 4; ++r) {
                    const int o = o0w + 16 * i + ((lane >> 4) << 2) + r;
                    const float bb = bm[o];
#pragma unroll
                    for (int j = 0; j < 4; ++j) {
                        const int n = n0 + 16 * j + row;
                        op[(size_t)o * NSP + n] = f2bf(acc[i][j][r] + bb);
                    }
                }
            }
#pragma unroll
            for (int i = 0; i < 4; ++i)
#pragma unroll
                for (int j = 0; j < 4; ++j) acc[i][j] = zero4();
        }

        __syncthreads();
        cur ^= 1;
    }
}

// ---------------------------------------------------------------------------
// Attention via MFMA: 1 wave (64 thr) per slice (b,ch,h), slice = 1600 bf16.
// S = Q K^T (40x40, M/N padded to 48, K padded to 64 via masked frags),
// wave-parallel softmax (4 shfl_xor per reduce), P -> LDS -> A-frag, O = P V.
// Q/K frags loaded directly from global (single-use data, L2-resident).
// ---------------------------------------------------------------------------
__global__ __launch_bounds__(64, 4) void attn_mfma(
    const u16* __restrict__ q, const u16* __restrict__ k,
    const u16* __restrict__ v, u16* __restrict__ a)
{
    const int s = blockIdx.x;
    const size_t base = (size_t)s * PL;
    const int l = threadIdx.x & 63;
    const int g = l >> 4;      // 16-lane group 0..3
    const int c = l & 15;      // lane-in-group

    __shared__ u16 vs[48][56];   // V transposed: vs[d][j]; stride 112B -> 2-way banks
    __shared__ u16 ps[48][56];   // P then O staging: ps[i][j]

    // zero vs[:][40..48) (j-pad that pairs with P=0 cols; must be finite 0)
#pragma unroll
    for (int it = 0; it < 3; ++it) {
        const int t = l + it * 64;                    // 0..191
        *(u32*)&vs[t >> 2][40 + ((t & 3) << 1)] = 0u;
    }

    // stage V transposed: V[j][d] -> vs[d][j]
#pragma unroll
    for (int it = 0; it < 7; ++it) {
        const int idx = l + it * 64;
        if (idx < 400) {
            const int j = idx / 10, d4 = (idx % 10) << 2;
            const ushort4 vv = *(const ushort4*)(v + base + j * 40 + d4);
            vs[d4 + 0][j] = vv.x; vs[d4 + 1][j] = vv.y;
            vs[d4 + 2][j] = vv.z; vs[d4 + 3][j] = vv.w;
        }
    }

    // ---- S = Q K^T ----
    f32x4 sacc[3][3];
#pragma unroll
    for (int mt = 0; mt < 3; ++mt)
#pragma unroll
        for (int jt = 0; jt < 3; ++jt) sacc[mt][jt] = zero4();

    {
        // kt = 0: d = g*8 .. g*8+7 (all valid)
        bf16x8 aq[3], bk0[3];
#pragma unroll
        for (int mt = 0; mt < 3; ++mt)
            aq[mt] = *(const bf16x8*)(q + base + (size_t)(mt * 16 + c) * 40 + g * 8);
#pragma unroll
        for (int jt = 0; jt < 3; ++jt)
            bk0[jt] = *(const bf16x8*)(k + base + (size_t)(jt * 16 + c) * 40 + g * 8);
#pragma unroll
        for (int mt = 0; mt < 3; ++mt)
#pragma unroll
            for (int jt = 0; jt < 3; ++jt)
                sacc[mt][jt] = __builtin_amdgcn_mfma_f32_16x16x32_bf16(
                    aq[mt], bk0[jt], sacc[mt][jt], 0, 0, 0);

        // kt = 1: d = 32 + g*8 + e, valid only for g==0 (d=32..39)
        bf16x8 aq1[3], bk1[3];
#pragma unroll
        for (int mt = 0; mt < 3; ++mt)
            aq1[mt] = (g == 0)
                ? *(const bf16x8*)(q + base + (size_t)(mt * 16 + c) * 40 + 32)
                : zero8();
#pragma unroll
        for (int jt = 0; jt < 3; ++jt)
            bk1[jt] = (g == 0)
                ? *(const bf16x8*)(k + base + (size_t)(jt * 16 + c) * 40 + 32)
                : zero8();
#pragma unroll
        for (int mt = 0; mt < 3; ++mt)
#pragma unroll
            for (int jt = 0; jt < 3; ++jt)
                sacc[mt][jt] = __builtin_amdgcn_mfma_f32_16x16x32_bf16(
                    aq1[mt], bk1[jt], sacc[mt][jt], 0, 0, 0);
    }

    // ---- wave-parallel softmax over j, write P (bf16) to ps ----
    // C-layout: lane holds col j = c + 16*jt, rows i = mt*16 + g*4 + r.
    // Row-reduce = shfl_xor over the 16 lanes sharing g.
    const bool val2 = (c < 8);   // jt=2 covers j=32..47; valid j<40
#pragma unroll
    for (int mt = 0; mt < 3; ++mt) {
#pragma unroll
        for (int r = 0; r < 4; ++r) {
            const float v0 = sacc[mt][0][r];
            const float v1 = sacc[mt][1][r];
            const float v2 = sacc[mt][2][r];
            float mx = fmaxf(fmaxf(v0, v1), val2 ? v2 : -1e30f);
#pragma unroll
            for (int off = 1; off < 16; off <<= 1)
                mx = fmaxf(mx, __shfl_xor(mx, off, 64));
            const float p0 = __expf((v0 - mx) * SCALE);
            const float p1 = __expf((v1 - mx) * SCALE);
            const float p2 = val2 ? __expf((v2 - mx) * SCALE) : 0.f;
            float sum = p0 + p1 + p2;
#pragma unroll
            for (int off = 1; off < 16; off <<= 1)
                sum += __shfl_xor(sum, off, 64);
            const float inv = 3.0f / sum;   // x3: three identical branches folded
            const int ri = mt * 16 + g * 4 + r;
            ps[ri][c]      = f2bf(p0 * inv);
            ps[ri][c + 16] = f2bf(p1 * inv);
            ps[ri][c + 32] = f2bf(p2 * inv);
        }
    }
    __syncthreads();

    // ---- O = P V ----
    f32x4 oacc[3][3];
#pragma unroll
    for (int mt = 0; mt < 3; ++mt)
#pragma unroll
        for (int nt = 0; nt < 3; ++nt) oacc[mt][nt] = zero4();

    {
        // kt = 0: j = g*8 .. +7
        bf16x8 pa[3], vb_[3];
#pragma unroll
        for (int mt = 0; mt < 3; ++mt)
            pa[mt] = *(const bf16x8*)&ps[mt * 16 + c][g * 8];
#pragma unroll
        for (int nt = 0; nt < 3; ++nt)
            vb_[nt] = *(const bf16x8*)&vs[nt * 16 + c][g * 8];
#pragma unroll
        for (int mt = 0; mt < 3; ++mt)
#pragma unroll
            for (int nt = 0; nt < 3; ++nt)
                oacc[mt][nt] = __builtin_amdgcn_mfma_f32_16x16x32_bf16(
                    pa[mt], vb_[nt], oacc[mt][nt], 0, 0, 0);

        // kt = 1: j = 32 + g*8 + e; groups 0,1 in-range (j<48), 2,3 zero
        bf16x8 pa1[3], vb1[3];
#pragma unroll
        for (int mt = 0; mt < 3; ++mt)
            pa1[mt] = (g < 2) ? *(const bf16x8*)&ps[mt * 16 + c][32 + g * 8] : zero8();
#pragma unroll
        for (int nt = 0; nt < 3; ++nt)
            vb1[nt] = (g < 2) ? *(const bf16x8*)&vs[nt * 16 + c][32 + g * 8] : zero8();
#pragma unroll
        for (int mt = 0; mt < 3; ++mt)
#pragma unroll
            for (int nt = 0; nt < 3; ++nt)
                oacc[mt][nt] = __builtin_amdgcn_mfma_f32_16x16x32_bf16(
                    pa1[mt], vb1[nt], oacc[mt][nt], 0, 0, 0);
    }
    __syncthreads();   // A/B frag reads done before ps is overwritten

    // ---- stage O in ps (valid region), then coalesced 8B stores ----
#pragma unroll
    for (int mt = 0; mt < 3; ++mt) {
        if (mt == 2 && g >= 2) continue;          // rows i>=40 discarded
#pragma unroll
        for (int r = 0; r < 4; ++r) {
            const int ri = mt * 16 + g * 4 + r;
#pragma unroll
            for (int nt = 0; nt < 3; ++nt) {
                if (nt == 2 && c >= 8) continue;  // cols d>=40 discarded
                ps[ri][nt * 16 + c] = f2bf(oacc[mt][nt][r]);
            }
        }
    }
    __syncthreads();

#pragma unroll
    for (int it = 0; it < 7; ++it) {
        const int idx = l + it * 64;
        if (idx < 400) {
            const int i = idx / 10, d4 = (idx % 10) << 2;
            *(ushort4*)(a + base + (size_t)idx * 4) = *(const ushort4*)&ps[i][d4];
        }
    }
}

// ---------------------------------------------------------------------------
// Proj via MFMA (unchanged from round 2)
// ---------------------------------------------------------------------------
__global__ __launch_bounds__(256, 2) void proj_mfma(
    const u16* __restrict__ a, const float* __restrict__ wp,
    const float* __restrict__ bp, float* __restrict__ out)
{
    const int b    = blockIdx.z;
    const int n0   = blockIdx.x * 64;
    const int t    = threadIdx.x;
    const int lane = t & 63;
    const int wid  = t >> 6;
    const int o0w  = wid * 64;

    __shared__ u16 xs[64][264];
    __shared__ u16 wsm[2][256][40];

    const u16* ab = a + (size_t)b * NC * NSP;

    {
        const int p  = t >> 4;
        const int nn = (t & 15) << 2;
#pragma unroll
        for (int it = 0; it < 8; ++it) {
            const int c = (it * 16 + p) * 2;
            const ushort4 ua = *(const ushort4*)(ab + (size_t)c * NSP + n0 + nn);
            const ushort4 ub = *(const ushort4*)(ab + (size_t)(c + 1) * NSP + n0 + nn);
            *(u32*)&xs[nn + 0][c] = (u32)ua.x | ((u32)ub.x << 16);
            *(u32*)&xs[nn + 1][c] = (u32)ua.y | ((u32)ub.y << 16);
            *(u32*)&xs[nn + 2][c] = (u32)ua.z | ((u32)ub.z << 16);
            *(u32*)&xs[nn + 3][c] = (u32)ua.w | ((u32)ub.w << 16);
        }
    }

    const int wo = t >> 3;
    const int wc = (t & 7) << 2;
    {
#pragma unroll
        for (int r = 0; r < 8; ++r) {
            const int o = r * 32 + wo;
            const float4 w4 = *(const float4*)(wp + (size_t)o * NC + wc);
            ushort4 pk;
            pk.x = f2bf(w4.x); pk.y = f2bf(w4.y); pk.z = f2bf(w4.z); pk.w = f2bf(w4.w);
            *(ushort4*)&wsm[0][o][wc] = pk;
        }
    }
    __syncthreads();

    f32x4 acc[4][4];
#pragma unroll
    for (int i = 0; i < 4; ++i)
#pragma unroll
        for (int j = 0; j < 4; ++j) acc[i][j] = zero4();

    const int row = lane & 15;
    const int kg  = (lane >> 4) << 3;

    int cur = 0;
    for (int step = 0; step < 8; ++step) {
        const bool pf = (step + 1 < 8);
        float4 wreg[8];
        if (pf) {
            const int kc2 = step + 1;
#pragma unroll
            for (int r = 0; r < 8; ++r) {
                const int o = r * 32 + wo;
                wreg[r] = *(const float4*)(wp + (size_t)o * NC + kc2 * 32 + wc);
            }
        }

        bf16x8 af[4], bfr[4];
#pragma unroll
        for (int i = 0; i < 4; ++i)
            af[i] = *(const bf16x8*)&wsm[cur][o0w + 16 * i + row][kg];
#pragma unroll
        for (int j = 0; j < 4; ++j)
            bfr[j] = *(const bf16x8*)&xs[16 * j + row][step * 32 + kg];
#pragma unroll
        for (int i = 0; i < 4; ++i)
#pragma unroll
            for (int j = 0; j < 4; ++j)
                acc[i][j] = __builtin_amdgcn_mfma_f32_16x16x32_bf16(
                    af[i], bfr[j], acc[i][j], 0, 0, 0);

        __syncthreads();

        if (pf) {
#pragma unroll
            for (int r = 0; r < 8; ++r) {
                const int o = r * 32 + wo;
                ushort4 pk;
                pk.x = f2bf(wreg[r].x); pk.y = f2bf(wreg[r].y);
                pk.z = f2bf(wreg[r].z); pk.w = f2bf(wreg[r].w);
                *(ushort4*)&wsm[cur ^ 1][o][wc] = pk;
            }
        }
        __syncthreads();
        cur ^= 1;
    }

    float* ob = out + (size_t)b * NC * NSP;
#pragma unroll
    for (int i = 0; i < 4; ++i) {
#pragma unroll
        for (int r = 0; r < 4; ++r) {
            const int o = o0w + 16 * i + ((lane >> 4) << 2) + r;
            const float bb = bp[o];
#pragma unroll
            for (int j = 0; j < 4; ++j) {
                const int n = n0 + 16 * j + row;
                ob[(size_t)o * NSP + n] = acc[i][j][r] + bb;
            }
        }
    }
}

extern "C" void kernel_launch(void* const* d_in, const int* in_sizes, int n_in,
                              void* d_out, int out_size, void* d_ws, size_t ws_size,
                              hipStream_t stream)
{
    const float* x  = (const float*)d_in[0];
    const float* wq = (const float*)d_in[1];
    const float* bq = (const float*)d_in[2];
    const float* wk = (const float*)d_in[3];
    const float* bk = (const float*)d_in[4];
    const float* wv = (const float*)d_in[5];
    const float* bv = (const float*)d_in[6];
    const float* wp = (const float*)d_in[7];
    const float* bp = (const float*)d_in[8];
    float* out = (float*)d_out;

    const size_t QE = (size_t)NB * NC * NSP;
    u16* qb = (u16*)d_ws;
    u16* kb = qb + QE;
    u16* vb = kb + QE;
    u16* ab = vb + QE;

    qkv_mfma<<<dim3(NSP / 64, 1, NB), 256, 0, stream>>>(
        x, wq, bq, wk, bk, wv, bv, qb, kb, vb);
    attn_mfma<<<dim3(NB * NC * NHH), 64, 0, stream>>>(qb, kb, vb, ab);
    proj_mfma<<<dim3(NSP / 64, 1, NB), 256, 0, stream>>>(ab, wp, bp, out);
}